// Round 10
// baseline (1799.002 us; speedup 1.0000x reference)
//
#include <hip/hip_runtime.h>
#include <math.h>

// Problem constants
#define Bn 2
#define Tn 2048
#define DM 2048
#define NH 16
#define NKV 4
#define HD 128

// ===================== split-bf16 MFMA GEMM =====================
// C[M,N] = A[M,2048] * W[N,2048]^T, fp32 in/out, fp32-accurate via
// a = a_hi + a_lo (bf16 pair): a*b ~= ah*bh + ah*bl + al*bh  (err ~2^-15).
// Tile: 128x128, BK=32, 4 waves, each wave a 64x64 quadrant (4x4 MFMA tiles).

typedef __attribute__((ext_vector_type(8))) short bf16x8;
typedef __attribute__((ext_vector_type(4))) float f32x4;

#define BM 128
#define BNt 128
#define BK 32
#define LROW 40   // ushorts per LDS row: 32 data + 8 pad (80B stride -> 2-way banks, free)

__device__ __forceinline__ void cvt_split(float f, unsigned short& hi, unsigned short& lo) {
  union { float x; unsigned u; } a, b, c;
  a.x = f;
  hi = (unsigned short)(a.u >> 16);        // truncated bf16 high part
  b.u = a.u & 0xFFFF0000u;                 // exact float value of hi
  c.x = f - b.x;                           // residual, |res| <= 2^-8 |f|
  lo = (unsigned short)(c.u >> 16);
}

__device__ __forceinline__ void gemm_core(
    const float* __restrict__ A, const float* __restrict__ W,
    float* __restrict__ C, int m0, int n0, int ldC) {
  __shared__ unsigned short Ah[BM * LROW], Al[BM * LROW];
  __shared__ unsigned short Bh[BNt * LROW], Bl[BNt * LROW];

  const int tid = threadIdx.x;
  const int lane = tid & 63;
  const int w = tid >> 6;          // wave 0..3
  const int wr = w >> 1;           // quadrant row
  const int wc = w & 1;            // quadrant col
  const int g = lane >> 4;         // k-octet group 0..3  (k = g*8 + i)
  const int r16 = lane & 15;       // row-in-16 for A/B frags, col for C/D

  f32x4 acc[4][4];
#pragma unroll
  for (int i = 0; i < 4; ++i)
#pragma unroll
    for (int j = 0; j < 4; ++j) acc[i][j] = (f32x4){0.f, 0.f, 0.f, 0.f};

  for (int kk = 0; kk < DM; kk += BK) {   // K = 2048 for every GEMM here
    // ---- global loads (fp32), coalesced: 8 lanes x float4 = 128B per tile row ----
    float4 av[4], bv[4];
#pragma unroll
    for (int i = 0; i < 4; ++i) {
      const int idx = tid + 256 * i;       // 0..1023 over 128 rows x 8 float4
      const int row = idx >> 3;
      const int k4 = (idx & 7) << 2;
      av[i] = *(const float4*)&A[(size_t)(m0 + row) * DM + kk + k4];
      bv[i] = *(const float4*)&W[(size_t)(n0 + row) * DM + kk + k4];
    }
    __syncthreads();                       // previous iteration done reading LDS
    // ---- convert to hi/lo bf16 and stage ----
#pragma unroll
    for (int i = 0; i < 4; ++i) {
      const int idx = tid + 256 * i;
      const int row = idx >> 3;
      const int s4 = (idx & 7) * 4;        // ushort offset within row (8B aligned)
      {
        unsigned short h0, l0, h1, l1, h2, l2, h3, l3;
        cvt_split(av[i].x, h0, l0); cvt_split(av[i].y, h1, l1);
        cvt_split(av[i].z, h2, l2); cvt_split(av[i].w, h3, l3);
        *(ushort4*)&Ah[row * LROW + s4] = make_ushort4(h0, h1, h2, h3);
        *(ushort4*)&Al[row * LROW + s4] = make_ushort4(l0, l1, l2, l3);
      }
      {
        unsigned short h0, l0, h1, l1, h2, l2, h3, l3;
        cvt_split(bv[i].x, h0, l0); cvt_split(bv[i].y, h1, l1);
        cvt_split(bv[i].z, h2, l2); cvt_split(bv[i].w, h3, l3);
        *(ushort4*)&Bh[row * LROW + s4] = make_ushort4(h0, h1, h2, h3);
        *(ushort4*)&Bl[row * LROW + s4] = make_ushort4(l0, l1, l2, l3);
      }
    }
    __syncthreads();

    // ---- MFMA compute: 16 tiles x 3 products ----
    bf16x8 ah[4], al[4];
#pragma unroll
    for (int mi = 0; mi < 4; ++mi) {
      const int ar = wr * 64 + mi * 16 + r16;
      ah[mi] = *(const bf16x8*)&Ah[ar * LROW + g * 8];
      al[mi] = *(const bf16x8*)&Al[ar * LROW + g * 8];
    }
#pragma unroll
    for (int ni = 0; ni < 4; ++ni) {
      const int brow = wc * 64 + ni * 16 + r16;
      bf16x8 bh = *(const bf16x8*)&Bh[brow * LROW + g * 8];
      bf16x8 bl = *(const bf16x8*)&Bl[brow * LROW + g * 8];
#pragma unroll
      for (int mi = 0; mi < 4; ++mi) {
        acc[mi][ni] = __builtin_amdgcn_mfma_f32_16x16x32_bf16(ah[mi], bh, acc[mi][ni], 0, 0, 0);
        acc[mi][ni] = __builtin_amdgcn_mfma_f32_16x16x32_bf16(ah[mi], bl, acc[mi][ni], 0, 0, 0);
        acc[mi][ni] = __builtin_amdgcn_mfma_f32_16x16x32_bf16(al[mi], bh, acc[mi][ni], 0, 0, 0);
      }
    }
  }

  // ---- epilogue: C/D layout col=lane&15, row=(lane>>4)*4+reg (m89-verified) ----
#pragma unroll
  for (int mi = 0; mi < 4; ++mi) {
#pragma unroll
    for (int r = 0; r < 4; ++r) {
      const size_t grow = (size_t)(m0 + wr * 64 + mi * 16 + g * 4 + r);
#pragma unroll
      for (int ni = 0; ni < 4; ++ni) {
        const int gcol = n0 + wc * 64 + ni * 16 + r16;
        C[grow * ldC + gcol] = acc[mi][ni][r];
      }
    }
  }
}

// Fused Q/K/V projection: grid.x = 24 (16 Q blocks, 4 K, 4 V), grid.y = 32.
__global__ __launch_bounds__(256) void qkv_kernel(
    const float* __restrict__ x, const float* __restrict__ Wq,
    const float* __restrict__ Wk, const float* __restrict__ Wv,
    float* __restrict__ Qo, float* __restrict__ Ko, float* __restrict__ Vo) {
  const int bx = blockIdx.x;
  const int m0 = blockIdx.y * BM;
  const float* W; float* C; int n0, ldC;
  if (bx < 16)      { W = Wq; C = Qo; n0 = bx * 128;        ldC = NH * HD; }
  else if (bx < 20) { W = Wk; C = Ko; n0 = (bx - 16) * 128; ldC = NKV * HD; }
  else              { W = Wv; C = Vo; n0 = (bx - 20) * 128; ldC = NKV * HD; }
  gemm_core(x, W, C, m0, n0, ldC);
}

// Output projection: out[4096,2048] = O[4096,2048] * Wo[2048,2048]^T
__global__ __launch_bounds__(256) void oproj_kernel(
    const float* __restrict__ O, const float* __restrict__ Wo,
    float* __restrict__ out) {
  gemm_core(O, Wo, out, blockIdx.y * BM, blockIdx.x * BNt, DM);
}

// ---------------- RMS norm along head_dim (in-place), rows of 128 ----------------
__global__ __launch_bounds__(256) void rmsnorm_kernel(
    float* __restrict__ X, const float* __restrict__ scale, int nrows) {
  const int row = blockIdx.x * 4 + (threadIdx.x >> 6);  // one wave per row
  const int lane = threadIdx.x & 63;
  float2 v = *(const float2*)&X[(size_t)row * HD + lane * 2];
  float ss = fmaf(v.x, v.x, v.y * v.y);
#pragma unroll
  for (int off = 1; off < 64; off <<= 1) ss += __shfl_xor(ss, off);
  const float r = rsqrtf(ss * (1.0f / HD) + 1e-6f);
  float2 sc = *(const float2*)&scale[lane * 2];
  v.x *= r * sc.x;
  v.y *= r * sc.y;
  *(float2*)&X[(size_t)row * HD + lane * 2] = v;
}

// ---------------- Flash-style causal GQA attention (fp32) ----------------
#define QT 32
#define KTILE 32
#define RPAD 132
#define SPAD 36

__global__ __launch_bounds__(256) void attn_kernel(
    const float* __restrict__ Qg, const float* __restrict__ Kg,
    const float* __restrict__ Vg, float* __restrict__ Og) {
  const int qt = blockIdx.x;
  const int h = blockIdx.y;
  const int b = blockIdx.z;
  const int kvh = h >> 2;  // h / (NH/NKV)
  const int tid = threadIdx.x;

  __shared__ float Qs[QT][RPAD];
  __shared__ float Ks[KTILE][RPAD];
  __shared__ float Vs[KTILE][RPAD];
  __shared__ float Ss[QT][SPAD];
  __shared__ float mrow[QT], lrow[QT], arow[QT];

  const int q0 = qt * QT;

  {
    const float* src = Qg + ((size_t)(b * Tn + q0)) * (NH * HD) + h * HD;
#pragma unroll
    for (int i = 0; i < 4; ++i) {
      const int idx = tid + 256 * i;
      const int r = idx >> 5;
      const int c = (idx & 31) << 2;
      *(float4*)&Qs[r][c] = *(const float4*)&src[(size_t)r * (NH * HD) + c];
    }
  }
  if (tid < QT) { mrow[tid] = -INFINITY; lrow[tid] = 0.f; arow[tid] = 0.f; }

  const int ry = tid >> 4;
  const int cx = tid & 15;
  const int r0 = ry * 2, r1 = r0 + 1;

  float o0[8] = {}, o1[8] = {};

  const int nkt = (q0 + QT - 1) / KTILE + 1;
  const float sscale = 0.08838834764831845f;  // 1/sqrt(128)

  for (int kt = 0; kt < nkt; ++kt) {
    const int k0 = kt * KTILE;
    const float* ksrc = Kg + ((size_t)(b * Tn + k0)) * (NKV * HD) + kvh * HD;
    const float* vsrc = Vg + ((size_t)(b * Tn + k0)) * (NKV * HD) + kvh * HD;
    float4 kreg[4], vreg[4];
#pragma unroll
    for (int i = 0; i < 4; ++i) {
      const int idx = tid + 256 * i;
      const int r = idx >> 5;
      const int c = (idx & 31) << 2;
      kreg[i] = *(const float4*)&ksrc[(size_t)r * (NKV * HD) + c];
      vreg[i] = *(const float4*)&vsrc[(size_t)r * (NKV * HD) + c];
    }
    __syncthreads();
#pragma unroll
    for (int i = 0; i < 4; ++i) {
      const int idx = tid + 256 * i;
      const int r = idx >> 5;
      const int c = (idx & 31) << 2;
      *(float4*)&Ks[r][c] = kreg[i];
      *(float4*)&Vs[r][c] = vreg[i];
    }
    __syncthreads();

    // Phase A: S = (Q K^T) * sscale
    {
      float s00 = 0.f, s01 = 0.f, s10 = 0.f, s11 = 0.f;
#pragma unroll
      for (int kx = 0; kx < HD; kx += 4) {
        float4 qa = *(const float4*)&Qs[r0][kx];
        float4 qb = *(const float4*)&Qs[r1][kx];
        float4 ka = *(const float4*)&Ks[cx][kx];
        float4 kb = *(const float4*)&Ks[cx + 16][kx];
        s00 += qa.x * ka.x + qa.y * ka.y + qa.z * ka.z + qa.w * ka.w;
        s01 += qa.x * kb.x + qa.y * kb.y + qa.z * kb.z + qa.w * kb.w;
        s10 += qb.x * ka.x + qb.y * ka.y + qb.z * ka.z + qb.w * ka.w;
        s11 += qb.x * kb.x + qb.y * kb.y + qb.z * kb.z + qb.w * kb.w;
      }
      Ss[r0][cx] = s00 * sscale;
      Ss[r0][cx + 16] = s01 * sscale;
      Ss[r1][cx] = s10 * sscale;
      Ss[r1][cx + 16] = s11 * sscale;
    }
    __syncthreads();

    // Phase B: online softmax
    {
      const int r = tid >> 3;
      const int c = tid & 7;
      const int qglob = q0 + r;
      float vals[4];
      float mloc = -INFINITY;
#pragma unroll
      for (int i = 0; i < 4; ++i) {
        const int j = c + 8 * i;
        float s = Ss[r][j];
        s = (k0 + j <= qglob) ? s : -INFINITY;
        vals[i] = s;
        mloc = fmaxf(mloc, s);
      }
      mloc = fmaxf(mloc, __shfl_xor(mloc, 1));
      mloc = fmaxf(mloc, __shfl_xor(mloc, 2));
      mloc = fmaxf(mloc, __shfl_xor(mloc, 4));
      const float mold = mrow[r];
      const float mnew = fmaxf(mold, mloc);
      float lsum = 0.f;
#pragma unroll
      for (int i = 0; i < 4; ++i) {
        const int j = c + 8 * i;
        const float p = __expf(vals[i] - mnew);
        Ss[r][j] = p;
        lsum += p;
      }
      lsum += __shfl_xor(lsum, 1);
      lsum += __shfl_xor(lsum, 2);
      lsum += __shfl_xor(lsum, 4);
      if (c == 0) {
        const float alpha = (mold > -INFINITY) ? __expf(mold - mnew) : 0.f;
        mrow[r] = mnew;
        arow[r] = alpha;
        lrow[r] = lrow[r] * alpha + lsum;
      }
    }
    __syncthreads();

    // Phase C: O = O*alpha + P*V
    {
      const float a0 = arow[r0], a1 = arow[r1];
#pragma unroll
      for (int j = 0; j < 8; ++j) { o0[j] *= a0; o1[j] *= a1; }
#pragma unroll 8
      for (int j = 0; j < KTILE; ++j) {
        const float p0 = Ss[r0][j];
        const float p1 = Ss[r1][j];
        float4 va = *(const float4*)&Vs[j][cx * 4];
        float4 vb = *(const float4*)&Vs[j][64 + cx * 4];
        o0[0] = fmaf(p0, va.x, o0[0]); o0[1] = fmaf(p0, va.y, o0[1]);
        o0[2] = fmaf(p0, va.z, o0[2]); o0[3] = fmaf(p0, va.w, o0[3]);
        o0[4] = fmaf(p0, vb.x, o0[4]); o0[5] = fmaf(p0, vb.y, o0[5]);
        o0[6] = fmaf(p0, vb.z, o0[6]); o0[7] = fmaf(p0, vb.w, o0[7]);
        o1[0] = fmaf(p1, va.x, o1[0]); o1[1] = fmaf(p1, va.y, o1[1]);
        o1[2] = fmaf(p1, va.z, o1[2]); o1[3] = fmaf(p1, va.w, o1[3]);
        o1[4] = fmaf(p1, vb.x, o1[4]); o1[5] = fmaf(p1, vb.y, o1[5]);
        o1[6] = fmaf(p1, vb.z, o1[6]); o1[7] = fmaf(p1, vb.w, o1[7]);
      }
    }
  }

  {
    const float inv0 = 1.f / lrow[r0];
    const float inv1 = 1.f / lrow[r1];
    float* dst = Og + ((size_t)(b * Tn + q0)) * (NH * HD) + h * HD;
    float4 wv;
    wv = make_float4(o0[0] * inv0, o0[1] * inv0, o0[2] * inv0, o0[3] * inv0);
    *(float4*)&dst[(size_t)r0 * (NH * HD) + cx * 4] = wv;
    wv = make_float4(o0[4] * inv0, o0[5] * inv0, o0[6] * inv0, o0[7] * inv0);
    *(float4*)&dst[(size_t)r0 * (NH * HD) + 64 + cx * 4] = wv;
    wv = make_float4(o1[0] * inv1, o1[1] * inv1, o1[2] * inv1, o1[3] * inv1);
    *(float4*)&dst[(size_t)r1 * (NH * HD) + cx * 4] = wv;
    wv = make_float4(o1[4] * inv1, o1[5] * inv1, o1[6] * inv1, o1[7] * inv1);
    *(float4*)&dst[(size_t)r1 * (NH * HD) + 64 + cx * 4] = wv;
  }
}

extern "C" void kernel_launch(void* const* d_in, const int* in_sizes, int n_in,
                              void* d_out, int out_size, void* d_ws, size_t ws_size,
                              hipStream_t stream) {
  const float* x = (const float*)d_in[0];
  const float* Wq = (const float*)d_in[1];
  const float* Wk = (const float*)d_in[2];
  const float* Wv = (const float*)d_in[3];
  const float* Wo = (const float*)d_in[4];
  const float* q_scale = (const float*)d_in[5];
  const float* k_scale = (const float*)d_in[6];
  float* out = (float*)d_out;

  const int R = Bn * Tn;  // 4096 token rows
  float* Q = (float*)d_ws;                        // [R][2048]
  float* K = Q + (size_t)R * (NH * HD);           // [R][512]
  float* V = K + (size_t)R * (NKV * HD);          // [R][512]
  float* O = V + (size_t)R * (NKV * HD);          // [R][2048]

  dim3 blk(256);
  // Fused Q/K/V projections via split-bf16 MFMA (768 blocks)
  qkv_kernel<<<dim3(24, R / BM), blk, 0, stream>>>(x, Wq, Wk, Wv, Q, K, V);
  // QK RMS-norm (in place)
  rmsnorm_kernel<<<dim3(R * NH / 4), blk, 0, stream>>>(Q, q_scale, R * NH);
  rmsnorm_kernel<<<dim3(R * NKV / 4), blk, 0, stream>>>(K, k_scale, R * NKV);
  // Causal GQA attention
  attn_kernel<<<dim3(Tn / QT, NH, Bn), blk, 0, stream>>>(Q, K, V, O);
  // Output projection via split-bf16 MFMA (512 blocks)
  oproj_kernel<<<dim3(DM / BNt, R / BM), blk, 0, stream>>>(O, Wo, out);
}

// Round 12
// 801.267 us; speedup vs baseline: 2.2452x; 2.2452x over previous
//
#include <hip/hip_runtime.h>
#include <math.h>

// Problem constants
#define Bn 2
#define Tn 2048
#define DM 2048
#define NH 16
#define NKV 4
#define HD 128

typedef __attribute__((ext_vector_type(8))) short bf16x8;
typedef __attribute__((ext_vector_type(4))) float f32x4;

__device__ __forceinline__ void cvt_split(float f, unsigned short& hi, unsigned short& lo) {
  union { float x; unsigned u; } a, b, c;
  a.x = f;
  hi = (unsigned short)(a.u >> 16);        // truncated bf16 high part
  b.u = a.u & 0xFFFF0000u;                 // exact float value of hi
  c.x = f - b.x;                           // residual
  lo = (unsigned short)(c.u >> 16);
}

// ===================== split-bf16 MFMA GEMM (HW-validated r10) ============
// VT=false: fp32 C write. VT=true: write hi/lo ushorts to pre-tiled Vt layout
//           Vt[b][kvh][kt][hl][d][32k]  (8192 ushorts per (kt) tile).
#define BM 128
#define BNt 128
#define LROW 40

template <bool VT>
__device__ __forceinline__ void gemm_core(
    const float* __restrict__ A, const float* __restrict__ W,
    void* __restrict__ Cout, int m0, int n0, int ldC) {
  __shared__ unsigned short Ah[BM * LROW], Al[BM * LROW];
  __shared__ unsigned short Bh[BNt * LROW], Bl[BNt * LROW];

  const int tid = threadIdx.x;
  const int lane = tid & 63;
  const int w = tid >> 6;
  const int wr = w >> 1;
  const int wc = w & 1;
  const int g = lane >> 4;
  const int r16 = lane & 15;

  f32x4 acc[4][4];
#pragma unroll
  for (int i = 0; i < 4; ++i)
#pragma unroll
    for (int j = 0; j < 4; ++j) acc[i][j] = (f32x4){0.f, 0.f, 0.f, 0.f};

  for (int kk = 0; kk < DM; kk += 32) {
    float4 av[4], bv[4];
#pragma unroll
    for (int i = 0; i < 4; ++i) {
      const int idx = tid + 256 * i;
      const int row = idx >> 3;
      const int k4 = (idx & 7) << 2;
      av[i] = *(const float4*)&A[(size_t)(m0 + row) * DM + kk + k4];
      bv[i] = *(const float4*)&W[(size_t)(n0 + row) * DM + kk + k4];
    }
    __syncthreads();
#pragma unroll
    for (int i = 0; i < 4; ++i) {
      const int idx = tid + 256 * i;
      const int row = idx >> 3;
      const int s4 = (idx & 7) * 4;
      {
        unsigned short h0, l0, h1, l1, h2, l2, h3, l3;
        cvt_split(av[i].x, h0, l0); cvt_split(av[i].y, h1, l1);
        cvt_split(av[i].z, h2, l2); cvt_split(av[i].w, h3, l3);
        *(ushort4*)&Ah[row * LROW + s4] = make_ushort4(h0, h1, h2, h3);
        *(ushort4*)&Al[row * LROW + s4] = make_ushort4(l0, l1, l2, l3);
      }
      {
        unsigned short h0, l0, h1, l1, h2, l2, h3, l3;
        cvt_split(bv[i].x, h0, l0); cvt_split(bv[i].y, h1, l1);
        cvt_split(bv[i].z, h2, l2); cvt_split(bv[i].w, h3, l3);
        *(ushort4*)&Bh[row * LROW + s4] = make_ushort4(h0, h1, h2, h3);
        *(ushort4*)&Bl[row * LROW + s4] = make_ushort4(l0, l1, l2, l3);
      }
    }
    __syncthreads();

    bf16x8 ah[4], al[4];
#pragma unroll
    for (int mi = 0; mi < 4; ++mi) {
      const int ar = wr * 64 + mi * 16 + r16;
      ah[mi] = *(const bf16x8*)&Ah[ar * LROW + g * 8];
      al[mi] = *(const bf16x8*)&Al[ar * LROW + g * 8];
    }
#pragma unroll
    for (int ni = 0; ni < 4; ++ni) {
      const int brow = wc * 64 + ni * 16 + r16;
      bf16x8 bh = *(const bf16x8*)&Bh[brow * LROW + g * 8];
      bf16x8 bl = *(const bf16x8*)&Bl[brow * LROW + g * 8];
#pragma unroll
      for (int mi = 0; mi < 4; ++mi) {
        acc[mi][ni] = __builtin_amdgcn_mfma_f32_16x16x32_bf16(ah[mi], bh, acc[mi][ni], 0, 0, 0);
        acc[mi][ni] = __builtin_amdgcn_mfma_f32_16x16x32_bf16(ah[mi], bl, acc[mi][ni], 0, 0, 0);
        acc[mi][ni] = __builtin_amdgcn_mfma_f32_16x16x32_bf16(al[mi], bh, acc[mi][ni], 0, 0, 0);
      }
    }
  }

  // ---- epilogue: C/D layout col=lane&15, row=(lane>>4)*4+reg ----
#pragma unroll
  for (int mi = 0; mi < 4; ++mi) {
#pragma unroll
    for (int r = 0; r < 4; ++r) {
      const int grow = m0 + wr * 64 + mi * 16 + g * 4 + r;
#pragma unroll
      for (int ni = 0; ni < 4; ++ni) {
        const int gcol = n0 + wc * 64 + ni * 16 + r16;
        const float val = acc[mi][ni][r];
        if constexpr (!VT) {
          ((float*)Cout)[(size_t)grow * ldC + gcol] = val;
        } else {
          // grow = b*Tn + t ; gcol = kvh*128 + d
          const int bb = grow >> 11, t = grow & 2047;
          const int kvh = gcol >> 7, d = gcol & 127;
          unsigned short hi, lo;
          cvt_split(val, hi, lo);
          unsigned short* C = (unsigned short*)Cout;
          const size_t base = ((size_t)((bb * NKV + kvh) * 64 + (t >> 5))) * 8192;
          C[base + d * 32 + (t & 31)] = hi;
          C[base + 4096 + d * 32 + (t & 31)] = lo;
        }
      }
    }
  }
}

// Fused Q/K/V projection: grid.x = 24 (16 Q, 4 K, 4 V), grid.y = 32.
__global__ __launch_bounds__(256) void qkv_kernel(
    const float* __restrict__ x, const float* __restrict__ Wq,
    const float* __restrict__ Wk, const float* __restrict__ Wv,
    float* __restrict__ Qo, float* __restrict__ Ko, unsigned short* __restrict__ Vt) {
  const int bx = blockIdx.x;
  const int m0 = blockIdx.y * BM;
  if (bx < 16)      gemm_core<false>(x, Wq, Qo, m0, bx * 128, NH * HD);
  else if (bx < 20) gemm_core<false>(x, Wk, Ko, m0, (bx - 16) * 128, NKV * HD);
  else              gemm_core<true >(x, Wv, Vt, m0, (bx - 20) * 128, 0);
}

__global__ __launch_bounds__(256) void oproj_kernel(
    const float* __restrict__ O, const float* __restrict__ Wo,
    float* __restrict__ out) {
  gemm_core<false>(O, Wo, out, blockIdx.y * BM, blockIdx.x * BNt, DM);
}

// ---------- RMS-norm + in-place cvt to hi|lo bf16 (row: 128 hi ush, 128 lo ush) ------
__global__ __launch_bounds__(256) void rmsnorm_cvt_kernel(
    float* __restrict__ X, const float* __restrict__ scale) {
  const int row = blockIdx.x * 4 + (threadIdx.x >> 6);  // one wave per row
  const int lane = threadIdx.x & 63;
  float2 v = *(const float2*)&X[(size_t)row * HD + lane * 2];
  float ss = fmaf(v.x, v.x, v.y * v.y);
#pragma unroll
  for (int off = 1; off < 64; off <<= 1) ss += __shfl_xor(ss, off);
  const float r = rsqrtf(ss * (1.0f / HD) + 1e-6f);
  float2 sc = *(const float2*)&scale[lane * 2];
  v.x *= r * sc.x;
  v.y *= r * sc.y;
  unsigned short h0, l0, h1, l1;
  cvt_split(v.x, h0, l0); cvt_split(v.y, h1, l1);
  unsigned short* rp = (unsigned short*)(X + (size_t)row * HD);
  *(ushort2*)&rp[lane * 2] = make_ushort2(h0, h1);   // all loads precede stores (wave lockstep)
  *(ushort2*)&rp[128 + lane * 2] = make_ushort2(l0, l1);
}

// ================= split-bf16 MFMA flash attention =================
// Block: 64 q-rows, 4 waves (16 q-rows each), K-tile 32. Q frags in regs.
// K LDS: 32 rows x 512B (hi|lo), XOR-swizzled chunks (verified bank-uniform).
// V LDS: linear copy of pre-tiled Vt[hl][d][32k] global tile (16 KB) -> no transpose.
#define AQT 64
#define AKT 32

__global__ __launch_bounds__(256) void attn_kernel(
    const unsigned short* __restrict__ Qus,   // [(b*Tn+t)*NH+h][256] hi|lo
    const unsigned short* __restrict__ Kus,   // [(b*Tn+t)*NKV+kvh][256]
    const unsigned short* __restrict__ Vt,    // [b][kvh][kt][hl][128][32]
    float* __restrict__ Og) {
  __shared__ unsigned short Ksh[32 * 256];      // 16 KB
  __shared__ unsigned short Vsh[1024 * 8];      // 16 KB ([hl][d][32k])
  __shared__ unsigned short Pws[4][2][16 * 40]; // 10 KB (per-wave P hi/lo)

  const int qt = blockIdx.x, h = blockIdx.y, b = blockIdx.z;
  const int kvh = h >> 2;
  const int tid = threadIdx.x;
  const int w = tid >> 6, lane = tid & 63;
  const int g = lane >> 4, r16 = lane & 15;
  const int q0 = qt * AQT;
  const float sscale = 0.08838834764831845f;

  // Q A-fragments (hi/lo), row = q0 + w*16 + r16, k = ks*32 + g*8 .. +8
  bf16x8 qh[4], ql[4];
  {
    const unsigned short* qrow =
        Qus + (size_t)(((b * Tn + q0 + w * 16 + r16) * NH) + h) * 256;
#pragma unroll
    for (int ks = 0; ks < 4; ++ks) {
      qh[ks] = *(const bf16x8*)(qrow + ks * 32 + g * 8);
      ql[ks] = *(const bf16x8*)(qrow + 128 + ks * 32 + g * 8);
    }
  }

  f32x4 o[8];
#pragma unroll
  for (int i = 0; i < 8; ++i) o[i] = (f32x4){0.f, 0.f, 0.f, 0.f};
  float m[4], l[4];
#pragma unroll
  for (int i = 0; i < 4; ++i) { m[i] = -INFINITY; l[i] = 0.f; }

  const int sw = (r16 & 7) << 4;
  const int ntile = (q0 + AQT) / AKT;
  const size_t vbase0 = (size_t)((b * NKV + kvh) * 64) * 8192;

  for (int kt = 0; kt < ntile; ++kt) {
    const int k0 = kt * AKT;
    // ---- global loads into regs (overlap prev tile compute) ----
    bf16x8 kreg[4], vreg[4];
    int kj[4], kcho[4];
#pragma unroll
    for (int i = 0; i < 4; ++i) {
      int c = tid + 256 * i;            // K: 1024 chunks of 16B (32 rows x 512B)
      kj[i] = c >> 5; kcho[i] = (c & 31) << 4;
      kreg[i] = *(const bf16x8*)(Kus +
          (size_t)(((b * Tn + k0 + kj[i]) * NKV) + kvh) * 256 + (kcho[i] >> 1));
      vreg[i] = *(const bf16x8*)(Vt + vbase0 + (size_t)kt * 8192 + (size_t)c * 8);
    }
    __syncthreads();   // previous tile fully consumed
    // ---- K -> LDS (swizzled rows), V -> LDS (linear) ----
#pragma unroll
    for (int i = 0; i < 4; ++i) {
      int byte = (kj[i] << 9) + (kcho[i] ^ ((kj[i] & 7) << 4));
      *(bf16x8*)((char*)Ksh + byte) = kreg[i];
      *(bf16x8*)((char*)Vsh + ((tid + 256 * i) << 4)) = vreg[i];
    }
    __syncthreads();

    // ---- QK^T: S[16q][32k], split-3 ----
    f32x4 s0 = (f32x4){0.f, 0.f, 0.f, 0.f};
    f32x4 s1 = (f32x4){0.f, 0.f, 0.f, 0.f};
    const char* Kb = (const char*)Ksh;
#pragma unroll
    for (int ks = 0; ks < 4; ++ks) {
      const int off = ks * 64 + g * 16;
      const int j0 = r16, j1 = 16 + r16;
      bf16x8 kh0 = *(const bf16x8*)(Kb + ((j0 << 9) + (off ^ sw)));
      bf16x8 kl0 = *(const bf16x8*)(Kb + ((j0 << 9) + ((256 + off) ^ sw)));
      bf16x8 kh1 = *(const bf16x8*)(Kb + ((j1 << 9) + (off ^ sw)));
      bf16x8 kl1 = *(const bf16x8*)(Kb + ((j1 << 9) + ((256 + off) ^ sw)));
      s0 = __builtin_amdgcn_mfma_f32_16x16x32_bf16(qh[ks], kh0, s0, 0, 0, 0);
      s0 = __builtin_amdgcn_mfma_f32_16x16x32_bf16(qh[ks], kl0, s0, 0, 0, 0);
      s0 = __builtin_amdgcn_mfma_f32_16x16x32_bf16(ql[ks], kh0, s0, 0, 0, 0);
      s1 = __builtin_amdgcn_mfma_f32_16x16x32_bf16(qh[ks], kh1, s1, 0, 0, 0);
      s1 = __builtin_amdgcn_mfma_f32_16x16x32_bf16(qh[ks], kl1, s1, 0, 0, 0);
      s1 = __builtin_amdgcn_mfma_f32_16x16x32_bf16(ql[ks], kh1, s1, 0, 0, 0);
    }

    // ---- mask + online softmax (lane holds q=g*4+rr, k=r16 / 16+r16) ----
    float mloc[4];
#pragma unroll
    for (int rr = 0; rr < 4; ++rr) {
      const int qg = q0 + w * 16 + g * 4 + rr;
      float a0 = (k0 + r16 <= qg) ? s0[rr] * sscale : -INFINITY;
      float a1 = (k0 + 16 + r16 <= qg) ? s1[rr] * sscale : -INFINITY;
      s0[rr] = a0; s1[rr] = a1;
      mloc[rr] = fmaxf(a0, a1);
    }
#pragma unroll
    for (int off = 1; off < 16; off <<= 1)
#pragma unroll
      for (int rr = 0; rr < 4; ++rr) mloc[rr] = fmaxf(mloc[rr], __shfl_xor(mloc[rr], off));
    float alpha[4], lsum[4];
#pragma unroll
    for (int rr = 0; rr < 4; ++rr) {
      const float mnew = fmaxf(m[rr], mloc[rr]);
      alpha[rr] = __expf(m[rr] - mnew);   // exp(-inf)=0 on first tile
      m[rr] = mnew;
      const float p0 = __expf(s0[rr] - mnew);
      const float p1 = __expf(s1[rr] - mnew);
      s0[rr] = p0; s1[rr] = p1;
      lsum[rr] = p0 + p1;
    }
#pragma unroll
    for (int off = 1; off < 16; off <<= 1)
#pragma unroll
      for (int rr = 0; rr < 4; ++rr) lsum[rr] += __shfl_xor(lsum[rr], off);
#pragma unroll
    for (int rr = 0; rr < 4; ++rr) l[rr] = l[rr] * alpha[rr] + lsum[rr];
#pragma unroll
    for (int dt = 0; dt < 8; ++dt)
#pragma unroll
      for (int rr = 0; rr < 4; ++rr) o[dt][rr] *= alpha[rr];

    // ---- P -> per-wave LDS (hi/lo), layout [q][40] ----
#pragma unroll
    for (int rr = 0; rr < 4; ++rr) {
      const int q = g * 4 + rr;
      unsigned short hh, ll;
      cvt_split(s0[rr], hh, ll);
      Pws[w][0][q * 40 + r16] = hh; Pws[w][1][q * 40 + r16] = ll;
      cvt_split(s1[rr], hh, ll);
      Pws[w][0][q * 40 + 16 + r16] = hh; Pws[w][1][q * 40 + 16 + r16] = ll;
    }
    // wave-private P region: same-wave LDS write->read is ordered (no barrier)

    // ---- PV: O[16][128] += P[16][32] * V[32][128], split-3 ----
    bf16x8 pah = *(const bf16x8*)&Pws[w][0][r16 * 40 + g * 8];
    bf16x8 pal = *(const bf16x8*)&Pws[w][1][r16 * 40 + g * 8];
#pragma unroll
    for (int dt = 0; dt < 8; ++dt) {
      const int d = dt * 16 + r16;
      const int vb = (d << 6) + (g << 4);          // Vsh[hl=0][d][k-chunk g]
      bf16x8 vh = *(const bf16x8*)((const char*)Vsh + vb);
      bf16x8 vl = *(const bf16x8*)((const char*)Vsh + 8192 + vb);
      o[dt] = __builtin_amdgcn_mfma_f32_16x16x32_bf16(pah, vh, o[dt], 0, 0, 0);
      o[dt] = __builtin_amdgcn_mfma_f32_16x16x32_bf16(pah, vl, o[dt], 0, 0, 0);
      o[dt] = __builtin_amdgcn_mfma_f32_16x16x32_bf16(pal, vh, o[dt], 0, 0, 0);
    }
  }

  // ---- epilogue ----
  float inv[4];
#pragma unroll
  for (int rr = 0; rr < 4; ++rr) inv[rr] = 1.f / l[rr];
#pragma unroll
  for (int dt = 0; dt < 8; ++dt)
#pragma unroll
    for (int rr = 0; rr < 4; ++rr) {
      Og[(size_t)(b * Tn + q0 + w * 16 + g * 4 + rr) * (NH * HD) + h * HD + dt * 16 + r16] =
          o[dt][rr] * inv[rr];
    }
}

extern "C" void kernel_launch(void* const* d_in, const int* in_sizes, int n_in,
                              void* d_out, int out_size, void* d_ws, size_t ws_size,
                              hipStream_t stream) {
  const float* x = (const float*)d_in[0];
  const float* Wq = (const float*)d_in[1];
  const float* Wk = (const float*)d_in[2];
  const float* Wv = (const float*)d_in[3];
  const float* Wo = (const float*)d_in[4];
  const float* q_scale = (const float*)d_in[5];
  const float* k_scale = (const float*)d_in[6];
  float* out = (float*)d_out;

  const int R = Bn * Tn;
  float* Q = (float*)d_ws;                                  // [R][2048] fp32 -> hi|lo ush
  float* K = Q + (size_t)R * (NH * HD);                     // [R][512]  fp32 -> hi|lo ush
  unsigned short* Vt = (unsigned short*)(K + (size_t)R * (NKV * HD));  // 8 MB pre-tiled
  float* O = (float*)(Vt + (size_t)Bn * NKV * 64 * 8192);   // [R][2048]

  dim3 blk(256);
  qkv_kernel<<<dim3(24, R / BM), blk, 0, stream>>>(x, Wq, Wk, Wv, Q, K, Vt);
  rmsnorm_cvt_kernel<<<dim3(R * NH / 4), blk, 0, stream>>>(Q, q_scale);
  rmsnorm_cvt_kernel<<<dim3(R * NKV / 4), blk, 0, stream>>>(K, k_scale);
  attn_kernel<<<dim3(Tn / AQT, NH, Bn), blk, 0, stream>>>(
      (const unsigned short*)Q, (const unsigned short*)K, Vt, O);
  oproj_kernel<<<dim3(DM / BNt, R / BM), blk, 0, stream>>>(O, Wo, out);
}

// Round 13
// 651.097 us; speedup vs baseline: 2.7630x; 1.2306x over previous
//
#include <hip/hip_runtime.h>
#include <math.h>

// Problem constants
#define Bn 2
#define Tn 2048
#define DM 2048
#define NH 16
#define NKV 4
#define HD 128

typedef __attribute__((ext_vector_type(8))) short bf16x8;
typedef __attribute__((ext_vector_type(4))) float f32x4;

__device__ __forceinline__ void cvt_split(float f, unsigned short& hi, unsigned short& lo) {
  union { float x; unsigned u; } a, b, c;
  a.x = f;
  hi = (unsigned short)(a.u >> 16);        // truncated bf16 high part
  b.u = a.u & 0xFFFF0000u;                 // exact float value of hi
  c.x = f - b.x;                           // residual
  lo = (unsigned short)(c.u >> 16);
}

// ===================== split-bf16 MFMA GEMM (HW-validated r10/r12) ============
// VT=false: fp32 C write. VT=true: write hi/lo ushorts to pre-tiled Vt layout
//           Vt[b][kvh][kt][hl][d][32k]  (8192 ushorts per (kt) tile).
#define BM 128
#define BNt 128
#define LROW 40

template <bool VT>
__device__ __forceinline__ void gemm_core(
    const float* __restrict__ A, const float* __restrict__ W,
    void* __restrict__ Cout, int m0, int n0, int ldC) {
  __shared__ unsigned short Ah[BM * LROW], Al[BM * LROW];
  __shared__ unsigned short Bh[BNt * LROW], Bl[BNt * LROW];

  const int tid = threadIdx.x;
  const int lane = tid & 63;
  const int w = tid >> 6;
  const int wr = w >> 1;
  const int wc = w & 1;
  const int g = lane >> 4;
  const int r16 = lane & 15;

  f32x4 acc[4][4];
#pragma unroll
  for (int i = 0; i < 4; ++i)
#pragma unroll
    for (int j = 0; j < 4; ++j) acc[i][j] = (f32x4){0.f, 0.f, 0.f, 0.f};

  for (int kk = 0; kk < DM; kk += 32) {
    float4 av[4], bv[4];
#pragma unroll
    for (int i = 0; i < 4; ++i) {
      const int idx = tid + 256 * i;
      const int row = idx >> 3;
      const int k4 = (idx & 7) << 2;
      av[i] = *(const float4*)&A[(size_t)(m0 + row) * DM + kk + k4];
      bv[i] = *(const float4*)&W[(size_t)(n0 + row) * DM + kk + k4];
    }
    __syncthreads();
#pragma unroll
    for (int i = 0; i < 4; ++i) {
      const int idx = tid + 256 * i;
      const int row = idx >> 3;
      const int s4 = (idx & 7) * 4;
      {
        unsigned short h0, l0, h1, l1, h2, l2, h3, l3;
        cvt_split(av[i].x, h0, l0); cvt_split(av[i].y, h1, l1);
        cvt_split(av[i].z, h2, l2); cvt_split(av[i].w, h3, l3);
        *(ushort4*)&Ah[row * LROW + s4] = make_ushort4(h0, h1, h2, h3);
        *(ushort4*)&Al[row * LROW + s4] = make_ushort4(l0, l1, l2, l3);
      }
      {
        unsigned short h0, l0, h1, l1, h2, l2, h3, l3;
        cvt_split(bv[i].x, h0, l0); cvt_split(bv[i].y, h1, l1);
        cvt_split(bv[i].z, h2, l2); cvt_split(bv[i].w, h3, l3);
        *(ushort4*)&Bh[row * LROW + s4] = make_ushort4(h0, h1, h2, h3);
        *(ushort4*)&Bl[row * LROW + s4] = make_ushort4(l0, l1, l2, l3);
      }
    }
    __syncthreads();

    bf16x8 ah[4], al[4];
#pragma unroll
    for (int mi = 0; mi < 4; ++mi) {
      const int ar = wr * 64 + mi * 16 + r16;
      ah[mi] = *(const bf16x8*)&Ah[ar * LROW + g * 8];
      al[mi] = *(const bf16x8*)&Al[ar * LROW + g * 8];
    }
#pragma unroll
    for (int ni = 0; ni < 4; ++ni) {
      const int brow = wc * 64 + ni * 16 + r16;
      bf16x8 bh = *(const bf16x8*)&Bh[brow * LROW + g * 8];
      bf16x8 bl = *(const bf16x8*)&Bl[brow * LROW + g * 8];
#pragma unroll
      for (int mi = 0; mi < 4; ++mi) {
        acc[mi][ni] = __builtin_amdgcn_mfma_f32_16x16x32_bf16(ah[mi], bh, acc[mi][ni], 0, 0, 0);
        acc[mi][ni] = __builtin_amdgcn_mfma_f32_16x16x32_bf16(ah[mi], bl, acc[mi][ni], 0, 0, 0);
        acc[mi][ni] = __builtin_amdgcn_mfma_f32_16x16x32_bf16(al[mi], bh, acc[mi][ni], 0, 0, 0);
      }
    }
  }

  // ---- epilogue: C/D layout col=lane&15, row=(lane>>4)*4+reg ----
#pragma unroll
  for (int mi = 0; mi < 4; ++mi) {
#pragma unroll
    for (int r = 0; r < 4; ++r) {
      const int grow = m0 + wr * 64 + mi * 16 + g * 4 + r;
#pragma unroll
      for (int ni = 0; ni < 4; ++ni) {
        const int gcol = n0 + wc * 64 + ni * 16 + r16;
        const float val = acc[mi][ni][r];
        if constexpr (!VT) {
          ((float*)Cout)[(size_t)grow * ldC + gcol] = val;
        } else {
          // grow = b*Tn + t ; gcol = kvh*128 + d
          const int bb = grow >> 11, t = grow & 2047;
          const int kvh = gcol >> 7, d = gcol & 127;
          unsigned short hi, lo;
          cvt_split(val, hi, lo);
          unsigned short* C = (unsigned short*)Cout;
          const size_t base = ((size_t)((bb * NKV + kvh) * 64 + (t >> 5))) * 8192;
          C[base + d * 32 + (t & 31)] = hi;
          C[base + 4096 + d * 32 + (t & 31)] = lo;
        }
      }
    }
  }
}

// Fused Q/K/V projection: grid.x = 24 (16 Q, 4 K, 4 V), grid.y = 32.
__global__ __launch_bounds__(256) void qkv_kernel(
    const float* __restrict__ x, const float* __restrict__ Wq,
    const float* __restrict__ Wk, const float* __restrict__ Wv,
    float* __restrict__ Qo, float* __restrict__ Ko, unsigned short* __restrict__ Vt) {
  const int bx = blockIdx.x;
  const int m0 = blockIdx.y * BM;
  if (bx < 16)      gemm_core<false>(x, Wq, Qo, m0, bx * 128, NH * HD);
  else if (bx < 20) gemm_core<false>(x, Wk, Ko, m0, (bx - 16) * 128, NKV * HD);
  else              gemm_core<true >(x, Wv, Vt, m0, (bx - 20) * 128, 0);
}

__global__ __launch_bounds__(256) void oproj_kernel(
    const float* __restrict__ O, const float* __restrict__ Wo,
    float* __restrict__ out) {
  gemm_core<false>(O, Wo, out, blockIdx.y * BM, blockIdx.x * BNt, DM);
}

// ---------- RMS-norm + in-place cvt to hi|lo bf16 (row: 128 hi ush, 128 lo ush) ------
__global__ __launch_bounds__(256) void rmsnorm_cvt_kernel(
    float* __restrict__ X, const float* __restrict__ scale) {
  const int row = blockIdx.x * 4 + (threadIdx.x >> 6);  // one wave per row
  const int lane = threadIdx.x & 63;
  float2 v = *(const float2*)&X[(size_t)row * HD + lane * 2];
  float ss = fmaf(v.x, v.x, v.y * v.y);
#pragma unroll
  for (int off = 1; off < 64; off <<= 1) ss += __shfl_xor(ss, off);
  const float r = rsqrtf(ss * (1.0f / HD) + 1e-6f);
  float2 sc = *(const float2*)&scale[lane * 2];
  v.x *= r * sc.x;
  v.y *= r * sc.y;
  unsigned short h0, l0, h1, l1;
  cvt_split(v.x, h0, l0); cvt_split(v.y, h1, l1);
  unsigned short* rp = (unsigned short*)(X + (size_t)row * HD);
  *(ushort2*)&rp[lane * 2] = make_ushort2(h0, h1);   // all loads precede stores (wave lockstep)
  *(ushort2*)&rp[128 + lane * 2] = make_ushort2(l0, l1);
}

// ================= split-bf16 MFMA flash attention =================
// Pairing: grid.x = 16; block handles q-tiles {bx, 31-bx} sequentially ->
// uniform 66 k-tile iterations per block (causal balance).
// K LDS: 32 rows x 512B, XOR-swizzled chunks (2-way banks).
// V LDS: rows of 40 ushorts (80B stride -> 20d%32 walks all bank-quads, 2-way).
#define AQT 64
#define AKT 32

__global__ __launch_bounds__(256) void attn_kernel(
    const unsigned short* __restrict__ Qus,   // [(b*Tn+t)*NH+h][256] hi|lo
    const unsigned short* __restrict__ Kus,   // [(b*Tn+t)*NKV+kvh][256]
    const unsigned short* __restrict__ Vt,    // [b][kvh][kt][hl][128][32]
    float* __restrict__ Og) {
  __shared__ unsigned short Ksh[32 * 256];      // 16 KB
  __shared__ unsigned short Vsh[2][128][40];    // 20 KB (80B rows, conflict-free)
  __shared__ unsigned short Pws[4][2][16 * 40]; // 10 KB (per-wave P hi/lo)

  const int bxp = blockIdx.x, h = blockIdx.y, b = blockIdx.z;
  const int kvh = h >> 2;
  const int tid = threadIdx.x;
  const int w = tid >> 6, lane = tid & 63;
  const int g = lane >> 4, r16 = lane & 15;
  const float sscale = 0.08838834764831845f;
  const int sw = (r16 & 7) << 4;
  const size_t vbase0 = (size_t)((b * NKV + kvh) * 64) * 8192;

  for (int ph = 0; ph < 2; ++ph) {
    const int qt = ph ? (31 - bxp) : bxp;
    const int q0 = qt * AQT;

    // Q A-fragments (hi/lo), row = q0 + w*16 + r16, k = ks*32 + g*8 .. +8
    bf16x8 qh[4], ql[4];
    {
      const unsigned short* qrow =
          Qus + (size_t)(((b * Tn + q0 + w * 16 + r16) * NH) + h) * 256;
#pragma unroll
      for (int ks = 0; ks < 4; ++ks) {
        qh[ks] = *(const bf16x8*)(qrow + ks * 32 + g * 8);
        ql[ks] = *(const bf16x8*)(qrow + 128 + ks * 32 + g * 8);
      }
    }

    f32x4 o[8];
#pragma unroll
    for (int i = 0; i < 8; ++i) o[i] = (f32x4){0.f, 0.f, 0.f, 0.f};
    float m[4], l[4];
#pragma unroll
    for (int i = 0; i < 4; ++i) { m[i] = -INFINITY; l[i] = 0.f; }

    const int ntile = 2 * qt + 2;

    for (int kt = 0; kt < ntile; ++kt) {
      const int k0 = kt * AKT;
      // ---- global loads into regs ----
      bf16x8 kreg[4], vreg[4];
      int kj[4], kcho[4];
#pragma unroll
      for (int i = 0; i < 4; ++i) {
        int c = tid + 256 * i;            // K: 1024 chunks of 16B (32 rows x 512B)
        kj[i] = c >> 5; kcho[i] = (c & 31) << 4;
        kreg[i] = *(const bf16x8*)(Kus +
            (size_t)(((b * Tn + k0 + kj[i]) * NKV) + kvh) * 256 + (kcho[i] >> 1));
        vreg[i] = *(const bf16x8*)(Vt + vbase0 + (size_t)kt * 8192 + (size_t)c * 8);
      }
      __syncthreads();   // previous tile fully consumed (also across ph boundary)
      // ---- K -> LDS (swizzled rows), V -> LDS (80B-stride rows) ----
#pragma unroll
      for (int i = 0; i < 4; ++i) {
        int byte = (kj[i] << 9) + (kcho[i] ^ ((kj[i] & 7) << 4));
        *(bf16x8*)((char*)Ksh + byte) = kreg[i];
        int c = tid + 256 * i;
        int hl = c >> 9, cc = c & 511;    // cc: 16B chunk among [128 d][4 slots]
        *(bf16x8*)&Vsh[hl][cc >> 2][(cc & 3) * 8] = vreg[i];
      }
      __syncthreads();

      // ---- QK^T: S[16q][32k], split-3 ----
      f32x4 s0 = (f32x4){0.f, 0.f, 0.f, 0.f};
      f32x4 s1 = (f32x4){0.f, 0.f, 0.f, 0.f};
      const char* Kb = (const char*)Ksh;
#pragma unroll
      for (int ks = 0; ks < 4; ++ks) {
        const int off = ks * 64 + g * 16;
        const int j0 = r16, j1 = 16 + r16;
        bf16x8 kh0 = *(const bf16x8*)(Kb + ((j0 << 9) + (off ^ sw)));
        bf16x8 kl0 = *(const bf16x8*)(Kb + ((j0 << 9) + ((256 + off) ^ sw)));
        bf16x8 kh1 = *(const bf16x8*)(Kb + ((j1 << 9) + (off ^ sw)));
        bf16x8 kl1 = *(const bf16x8*)(Kb + ((j1 << 9) + ((256 + off) ^ sw)));
        s0 = __builtin_amdgcn_mfma_f32_16x16x32_bf16(qh[ks], kh0, s0, 0, 0, 0);
        s0 = __builtin_amdgcn_mfma_f32_16x16x32_bf16(qh[ks], kl0, s0, 0, 0, 0);
        s0 = __builtin_amdgcn_mfma_f32_16x16x32_bf16(ql[ks], kh0, s0, 0, 0, 0);
        s1 = __builtin_amdgcn_mfma_f32_16x16x32_bf16(qh[ks], kh1, s1, 0, 0, 0);
        s1 = __builtin_amdgcn_mfma_f32_16x16x32_bf16(qh[ks], kl1, s1, 0, 0, 0);
        s1 = __builtin_amdgcn_mfma_f32_16x16x32_bf16(ql[ks], kh1, s1, 0, 0, 0);
      }

      // ---- mask + online softmax (lane holds q=g*4+rr, k=r16 / 16+r16) ----
      float mloc[4];
#pragma unroll
      for (int rr = 0; rr < 4; ++rr) {
        const int qg = q0 + w * 16 + g * 4 + rr;
        float a0 = (k0 + r16 <= qg) ? s0[rr] * sscale : -INFINITY;
        float a1 = (k0 + 16 + r16 <= qg) ? s1[rr] * sscale : -INFINITY;
        s0[rr] = a0; s1[rr] = a1;
        mloc[rr] = fmaxf(a0, a1);
      }
#pragma unroll
      for (int off = 1; off < 16; off <<= 1)
#pragma unroll
        for (int rr = 0; rr < 4; ++rr) mloc[rr] = fmaxf(mloc[rr], __shfl_xor(mloc[rr], off));
      float alpha[4], lsum[4];
#pragma unroll
      for (int rr = 0; rr < 4; ++rr) {
        const float mnew = fmaxf(m[rr], mloc[rr]);
        alpha[rr] = __expf(m[rr] - mnew);   // exp(-inf)=0 on first tile
        m[rr] = mnew;
        const float p0 = __expf(s0[rr] - mnew);
        const float p1 = __expf(s1[rr] - mnew);
        s0[rr] = p0; s1[rr] = p1;
        lsum[rr] = p0 + p1;
      }
#pragma unroll
      for (int off = 1; off < 16; off <<= 1)
#pragma unroll
        for (int rr = 0; rr < 4; ++rr) lsum[rr] += __shfl_xor(lsum[rr], off);
#pragma unroll
      for (int rr = 0; rr < 4; ++rr) l[rr] = l[rr] * alpha[rr] + lsum[rr];
#pragma unroll
      for (int dt = 0; dt < 8; ++dt)
#pragma unroll
        for (int rr = 0; rr < 4; ++rr) o[dt][rr] *= alpha[rr];

      // ---- P -> per-wave LDS (hi/lo), layout [q][40] ----
#pragma unroll
      for (int rr = 0; rr < 4; ++rr) {
        const int q = g * 4 + rr;
        unsigned short hh, ll;
        cvt_split(s0[rr], hh, ll);
        Pws[w][0][q * 40 + r16] = hh; Pws[w][1][q * 40 + r16] = ll;
        cvt_split(s1[rr], hh, ll);
        Pws[w][0][q * 40 + 16 + r16] = hh; Pws[w][1][q * 40 + 16 + r16] = ll;
      }
      // wave-private P region: same-wave LDS write->read is ordered (no barrier)

      // ---- PV: O[16][128] += P[16][32] * V[32][128], split-3 ----
      bf16x8 pah = *(const bf16x8*)&Pws[w][0][r16 * 40 + g * 8];
      bf16x8 pal = *(const bf16x8*)&Pws[w][1][r16 * 40 + g * 8];
#pragma unroll
      for (int dt = 0; dt < 8; ++dt) {
        const int d = dt * 16 + r16;
        bf16x8 vh = *(const bf16x8*)&Vsh[0][d][g * 8];
        bf16x8 vl = *(const bf16x8*)&Vsh[1][d][g * 8];
        o[dt] = __builtin_amdgcn_mfma_f32_16x16x32_bf16(pah, vh, o[dt], 0, 0, 0);
        o[dt] = __builtin_amdgcn_mfma_f32_16x16x32_bf16(pah, vl, o[dt], 0, 0, 0);
        o[dt] = __builtin_amdgcn_mfma_f32_16x16x32_bf16(pal, vh, o[dt], 0, 0, 0);
      }
    }

    // ---- epilogue for this q-tile ----
    float inv[4];
#pragma unroll
    for (int rr = 0; rr < 4; ++rr) inv[rr] = 1.f / l[rr];
#pragma unroll
    for (int dt = 0; dt < 8; ++dt)
#pragma unroll
      for (int rr = 0; rr < 4; ++rr) {
        Og[(size_t)(b * Tn + q0 + w * 16 + g * 4 + rr) * (NH * HD) + h * HD + dt * 16 + r16] =
            o[dt][rr] * inv[rr];
      }
  }
}

extern "C" void kernel_launch(void* const* d_in, const int* in_sizes, int n_in,
                              void* d_out, int out_size, void* d_ws, size_t ws_size,
                              hipStream_t stream) {
  const float* x = (const float*)d_in[0];
  const float* Wq = (const float*)d_in[1];
  const float* Wk = (const float*)d_in[2];
  const float* Wv = (const float*)d_in[3];
  const float* Wo = (const float*)d_in[4];
  const float* q_scale = (const float*)d_in[5];
  const float* k_scale = (const float*)d_in[6];
  float* out = (float*)d_out;

  const int R = Bn * Tn;
  float* Q = (float*)d_ws;                                  // [R][2048] fp32 -> hi|lo ush
  float* K = Q + (size_t)R * (NH * HD);                     // [R][512]  fp32 -> hi|lo ush
  unsigned short* Vt = (unsigned short*)(K + (size_t)R * (NKV * HD));  // 8 MB pre-tiled
  float* O = (float*)(Vt + (size_t)Bn * NKV * 64 * 8192);   // [R][2048]

  dim3 blk(256);
  qkv_kernel<<<dim3(24, R / BM), blk, 0, stream>>>(x, Wq, Wk, Wv, Q, K, Vt);
  rmsnorm_cvt_kernel<<<dim3(R * NH / 4), blk, 0, stream>>>(Q, q_scale);
  rmsnorm_cvt_kernel<<<dim3(R * NKV / 4), blk, 0, stream>>>(K, k_scale);
  attn_kernel<<<dim3(16, NH, Bn), blk, 0, stream>>>(
      (const unsigned short*)Q, (const unsigned short*)K, Vt, O);
  oproj_kernel<<<dim3(DM / BNt, R / BM), blk, 0, stream>>>(O, Wo, out);
}

// Round 14
// 632.972 us; speedup vs baseline: 2.8421x; 1.0286x over previous
//
#include <hip/hip_runtime.h>
#include <math.h>

// Problem constants
#define Bn 2
#define Tn 2048
#define DM 2048
#define NH 16
#define NKV 4
#define HD 128

typedef __attribute__((ext_vector_type(8))) short bf16x8;
typedef __attribute__((ext_vector_type(4))) float f32x4;

__device__ __forceinline__ void cvt_split(float f, unsigned short& hi, unsigned short& lo) {
  union { float x; unsigned u; } a, b, c;
  a.x = f;
  hi = (unsigned short)(a.u >> 16);        // truncated bf16 high part
  b.u = a.u & 0xFFFF0000u;                 // exact float value of hi
  c.x = f - b.x;                           // residual
  lo = (unsigned short)(c.u >> 16);
}

// async global->LDS, 16B per lane: LDS dest = uniform base + lane*16
__device__ __forceinline__ void gload16(const unsigned short* g, unsigned short* l) {
  __builtin_amdgcn_global_load_lds(
      (const __attribute__((address_space(1))) void*)g,
      (__attribute__((address_space(3))) void*)l, 16, 0, 0);
}

// ---------- prep: split fp32 -> hi/lo bf16 (vectorized, grid-stride) ----------
__global__ __launch_bounds__(256) void split_kernel(
    const float* __restrict__ src, unsigned short* __restrict__ h,
    unsigned short* __restrict__ l, int n4) {
  int i = blockIdx.x * 256 + threadIdx.x;
  const int stride = gridDim.x * 256;
  for (; i < n4; i += stride) {
    float4 v = ((const float4*)src)[i];
    ushort4 hh, ll;
    cvt_split(v.x, hh.x, ll.x); cvt_split(v.y, hh.y, ll.y);
    cvt_split(v.z, hh.z, ll.z); cvt_split(v.w, hh.w, ll.w);
    ((ushort4*)h)[i] = hh;
    ((ushort4*)l)[i] = ll;
  }
}

// ===================== split-bf16 MFMA GEMM, DMA-staged =====================
// C[M,N] = A[M,2048] * B[N,2048]^T. Tile 128x128, BK=32, 4 waves.
// B (and A if APRE) are pre-split hi/lo ushort buffers, staged via
// global_load_lds into linear LDS [128][32] (64B rows; b128 reads uniform 8/bank).
// APRE=false: A is fp32, cvt_split in-loop. VT: write V to pre-tiled Vt.
template <bool APRE, bool VT>
__device__ __forceinline__ void gemm_core(
    const float* __restrict__ Af,
    const unsigned short* __restrict__ Agh, const unsigned short* __restrict__ Agl,
    const unsigned short* __restrict__ Bgh, const unsigned short* __restrict__ Bgl,
    void* __restrict__ Cout, int m0, int n0, int ldC) {
  __shared__ unsigned short lA[2][128 * 32];   // [hl][row*32]  8KB each
  __shared__ unsigned short lB[2][128 * 32];

  const int tid = threadIdx.x;
  const int lane = tid & 63;
  const int w = tid >> 6;
  const int wr = w >> 1, wc = w & 1;
  const int g = lane >> 4, r16 = lane & 15;
  const int lrow = lane >> 2;                  // gload16: row-in-16B-chunks
  const int lch = (lane & 3) * 8;              // k-offset (ushorts)
  const int b0 = w * 32, b1 = w * 32 + 16;     // per-wave staging rows

  f32x4 acc[4][4];
#pragma unroll
  for (int i = 0; i < 4; ++i)
#pragma unroll
    for (int j = 0; j < 4; ++j) acc[i][j] = (f32x4){0.f, 0.f, 0.f, 0.f};

  for (int kk = 0; kk < DM; kk += 32) {
    float4 av[4];
    if constexpr (!APRE) {
#pragma unroll
      for (int i = 0; i < 4; ++i) {
        const int idx = tid + 256 * i;
        const int row = idx >> 3;
        const int k4 = (idx & 7) << 2;
        av[i] = *(const float4*)&Af[(size_t)(m0 + row) * DM + kk + k4];
      }
    }
    __syncthreads();   // previous iteration's LDS reads complete
    // ---- B (and A if pre-split) staged via DMA: 16 rows x 64B per call ----
    gload16(&Bgh[(size_t)(n0 + b0 + lrow) * DM + kk + lch], &lB[0][b0 * 32]);
    gload16(&Bgh[(size_t)(n0 + b1 + lrow) * DM + kk + lch], &lB[0][b1 * 32]);
    gload16(&Bgl[(size_t)(n0 + b0 + lrow) * DM + kk + lch], &lB[1][b0 * 32]);
    gload16(&Bgl[(size_t)(n0 + b1 + lrow) * DM + kk + lch], &lB[1][b1 * 32]);
    if constexpr (APRE) {
      gload16(&Agh[(size_t)(m0 + b0 + lrow) * DM + kk + lch], &lA[0][b0 * 32]);
      gload16(&Agh[(size_t)(m0 + b1 + lrow) * DM + kk + lch], &lA[0][b1 * 32]);
      gload16(&Agl[(size_t)(m0 + b0 + lrow) * DM + kk + lch], &lA[1][b0 * 32]);
      gload16(&Agl[(size_t)(m0 + b1 + lrow) * DM + kk + lch], &lA[1][b1 * 32]);
    } else {
#pragma unroll
      for (int i = 0; i < 4; ++i) {
        const int idx = tid + 256 * i;
        const int row = idx >> 3;
        const int s4 = (idx & 7) * 4;
        unsigned short h0, l0, h1, l1, h2, l2, h3, l3;
        cvt_split(av[i].x, h0, l0); cvt_split(av[i].y, h1, l1);
        cvt_split(av[i].z, h2, l2); cvt_split(av[i].w, h3, l3);
        *(ushort4*)&lA[0][row * 32 + s4] = make_ushort4(h0, h1, h2, h3);
        *(ushort4*)&lA[1][row * 32 + s4] = make_ushort4(l0, l1, l2, l3);
      }
    }
    __syncthreads();   // drains vmcnt (DMA landed) + lgkm

    // ---- MFMA: 16 tiles x 3 products ----
    bf16x8 ah[4], al[4];
#pragma unroll
    for (int mi = 0; mi < 4; ++mi) {
      const int ar = wr * 64 + mi * 16 + r16;
      ah[mi] = *(const bf16x8*)&lA[0][ar * 32 + g * 8];
      al[mi] = *(const bf16x8*)&lA[1][ar * 32 + g * 8];
    }
#pragma unroll
    for (int ni = 0; ni < 4; ++ni) {
      const int brow = wc * 64 + ni * 16 + r16;
      bf16x8 bh = *(const bf16x8*)&lB[0][brow * 32 + g * 8];
      bf16x8 bl = *(const bf16x8*)&lB[1][brow * 32 + g * 8];
#pragma unroll
      for (int mi = 0; mi < 4; ++mi) {
        acc[mi][ni] = __builtin_amdgcn_mfma_f32_16x16x32_bf16(ah[mi], bh, acc[mi][ni], 0, 0, 0);
        acc[mi][ni] = __builtin_amdgcn_mfma_f32_16x16x32_bf16(ah[mi], bl, acc[mi][ni], 0, 0, 0);
        acc[mi][ni] = __builtin_amdgcn_mfma_f32_16x16x32_bf16(al[mi], bh, acc[mi][ni], 0, 0, 0);
      }
    }
  }

  // ---- epilogue: C/D layout col=lane&15, row=(lane>>4)*4+reg (HW-validated) ----
#pragma unroll
  for (int mi = 0; mi < 4; ++mi) {
#pragma unroll
    for (int r = 0; r < 4; ++r) {
      const int grow = m0 + wr * 64 + mi * 16 + g * 4 + r;
#pragma unroll
      for (int ni = 0; ni < 4; ++ni) {
        const int gcol = n0 + wc * 64 + ni * 16 + r16;
        const float val = acc[mi][ni][r];
        if constexpr (!VT) {
          ((float*)Cout)[(size_t)grow * ldC + gcol] = val;
        } else {
          // grow = b*Tn + t ; gcol = kvh*128 + d  -> Vt[b][kvh][t/32][hl][d][t%32]
          const int bb = grow >> 11, t = grow & 2047;
          const int kvh = gcol >> 7, d = gcol & 127;
          unsigned short hi, lo;
          cvt_split(val, hi, lo);
          unsigned short* C = (unsigned short*)Cout;
          const size_t base = ((size_t)((bb * NKV + kvh) * 64 + (t >> 5))) * 8192;
          C[base + d * 32 + (t & 31)] = hi;
          C[base + 4096 + d * 32 + (t & 31)] = lo;
        }
      }
    }
  }
}

// Fused Q/K/V projection: grid.x = 24 (16 Q, 4 K, 4 V), grid.y = 32.
__global__ __launch_bounds__(256) void qkv_kernel(
    const float* __restrict__ x,
    const unsigned short* __restrict__ Wqh, const unsigned short* __restrict__ Wql,
    const unsigned short* __restrict__ Wkh, const unsigned short* __restrict__ Wkl,
    const unsigned short* __restrict__ Wvh, const unsigned short* __restrict__ Wvl,
    float* __restrict__ Qo, float* __restrict__ Ko, unsigned short* __restrict__ Vt) {
  const int bx = blockIdx.x;
  const int m0 = blockIdx.y * 128;
  if (bx < 16)      gemm_core<false, false>(x, nullptr, nullptr, Wqh, Wql, Qo, m0, bx * 128, NH * HD);
  else if (bx < 20) gemm_core<false, false>(x, nullptr, nullptr, Wkh, Wkl, Ko, m0, (bx - 16) * 128, NKV * HD);
  else              gemm_core<false, true >(x, nullptr, nullptr, Wvh, Wvl, Vt, m0, (bx - 20) * 128, 0);
}

// Output projection: A = attn output pre-split (Oh/Ol), B = Wo pre-split.
__global__ __launch_bounds__(256) void oproj_kernel(
    const unsigned short* __restrict__ Oh, const unsigned short* __restrict__ Ol,
    const unsigned short* __restrict__ Woh, const unsigned short* __restrict__ Wol,
    float* __restrict__ out) {
  gemm_core<true, false>(nullptr, Oh, Ol, Woh, Wol, out, blockIdx.y * 128, blockIdx.x * 128, DM);
}

// ---------- RMS-norm + in-place cvt to hi|lo bf16 (row: 128 hi ush, 128 lo ush) ------
__global__ __launch_bounds__(256) void rmsnorm_cvt_kernel(
    float* __restrict__ X, const float* __restrict__ scale) {
  const int row = blockIdx.x * 4 + (threadIdx.x >> 6);  // one wave per head-row
  const int lane = threadIdx.x & 63;
  float2 v = *(const float2*)&X[(size_t)row * HD + lane * 2];
  float ss = fmaf(v.x, v.x, v.y * v.y);
#pragma unroll
  for (int off = 1; off < 64; off <<= 1) ss += __shfl_xor(ss, off);
  const float r = rsqrtf(ss * (1.0f / HD) + 1e-6f);
  float2 sc = *(const float2*)&scale[lane * 2];
  v.x *= r * sc.x;
  v.y *= r * sc.y;
  unsigned short h0, l0, h1, l1;
  cvt_split(v.x, h0, l0); cvt_split(v.y, h1, l1);
  unsigned short* rp = (unsigned short*)(X + (size_t)row * HD);
  *(ushort2*)&rp[lane * 2] = make_ushort2(h0, h1);   // loads precede stores (wave lockstep)
  *(ushort2*)&rp[128 + lane * 2] = make_ushort2(l0, l1);
}

// ================= split-bf16 MFMA flash attention (r13-validated) =================
// grid.x = 16; block handles q-tiles {bx, 31-bx} (causal balance, 66 iters).
// K LDS: 32 x 512B XOR-swizzled. V LDS: 80B rows (conflict-free).
// Epilogue writes O as pre-split hi/lo ushorts (feeds oproj's DMA path).
#define AQT 64
#define AKT 32

__global__ __launch_bounds__(256) void attn_kernel(
    const unsigned short* __restrict__ Qus,   // [(b*Tn+t)*NH+h][256] hi|lo
    const unsigned short* __restrict__ Kus,   // [(b*Tn+t)*NKV+kvh][256]
    const unsigned short* __restrict__ Vt,    // [b][kvh][kt][hl][128][32]
    unsigned short* __restrict__ Oh, unsigned short* __restrict__ Ol) {
  __shared__ unsigned short Ksh[32 * 256];      // 16 KB
  __shared__ unsigned short Vsh[2][128][40];    // 20 KB
  __shared__ unsigned short Pws[4][2][16 * 40]; // 10 KB

  const int bxp = blockIdx.x, h = blockIdx.y, b = blockIdx.z;
  const int kvh = h >> 2;
  const int tid = threadIdx.x;
  const int w = tid >> 6, lane = tid & 63;
  const int g = lane >> 4, r16 = lane & 15;
  const float sscale = 0.08838834764831845f;
  const int sw = (r16 & 7) << 4;
  const size_t vbase0 = (size_t)((b * NKV + kvh) * 64) * 8192;

  for (int ph = 0; ph < 2; ++ph) {
    const int qt = ph ? (31 - bxp) : bxp;
    const int q0 = qt * AQT;

    bf16x8 qh[4], ql[4];
    {
      const unsigned short* qrow =
          Qus + (size_t)(((b * Tn + q0 + w * 16 + r16) * NH) + h) * 256;
#pragma unroll
      for (int ks = 0; ks < 4; ++ks) {
        qh[ks] = *(const bf16x8*)(qrow + ks * 32 + g * 8);
        ql[ks] = *(const bf16x8*)(qrow + 128 + ks * 32 + g * 8);
      }
    }

    f32x4 o[8];
#pragma unroll
    for (int i = 0; i < 8; ++i) o[i] = (f32x4){0.f, 0.f, 0.f, 0.f};
    float m[4], l[4];
#pragma unroll
    for (int i = 0; i < 4; ++i) { m[i] = -INFINITY; l[i] = 0.f; }

    const int ntile = 2 * qt + 2;

    for (int kt = 0; kt < ntile; ++kt) {
      const int k0 = kt * AKT;
      bf16x8 kreg[4], vreg[4];
      int kj[4], kcho[4];
#pragma unroll
      for (int i = 0; i < 4; ++i) {
        int c = tid + 256 * i;
        kj[i] = c >> 5; kcho[i] = (c & 31) << 4;
        kreg[i] = *(const bf16x8*)(Kus +
            (size_t)(((b * Tn + k0 + kj[i]) * NKV) + kvh) * 256 + (kcho[i] >> 1));
        vreg[i] = *(const bf16x8*)(Vt + vbase0 + (size_t)kt * 8192 + (size_t)c * 8);
      }
      __syncthreads();
#pragma unroll
      for (int i = 0; i < 4; ++i) {
        int byte = (kj[i] << 9) + (kcho[i] ^ ((kj[i] & 7) << 4));
        *(bf16x8*)((char*)Ksh + byte) = kreg[i];
        int c = tid + 256 * i;
        int hl = c >> 9, cc = c & 511;
        *(bf16x8*)&Vsh[hl][cc >> 2][(cc & 3) * 8] = vreg[i];
      }
      __syncthreads();

      f32x4 s0 = (f32x4){0.f, 0.f, 0.f, 0.f};
      f32x4 s1 = (f32x4){0.f, 0.f, 0.f, 0.f};
      const char* Kb = (const char*)Ksh;
#pragma unroll
      for (int ks = 0; ks < 4; ++ks) {
        const int off = ks * 64 + g * 16;
        const int j0 = r16, j1 = 16 + r16;
        bf16x8 kh0 = *(const bf16x8*)(Kb + ((j0 << 9) + (off ^ sw)));
        bf16x8 kl0 = *(const bf16x8*)(Kb + ((j0 << 9) + ((256 + off) ^ sw)));
        bf16x8 kh1 = *(const bf16x8*)(Kb + ((j1 << 9) + (off ^ sw)));
        bf16x8 kl1 = *(const bf16x8*)(Kb + ((j1 << 9) + ((256 + off) ^ sw)));
        s0 = __builtin_amdgcn_mfma_f32_16x16x32_bf16(qh[ks], kh0, s0, 0, 0, 0);
        s0 = __builtin_amdgcn_mfma_f32_16x16x32_bf16(qh[ks], kl0, s0, 0, 0, 0);
        s0 = __builtin_amdgcn_mfma_f32_16x16x32_bf16(ql[ks], kh0, s0, 0, 0, 0);
        s1 = __builtin_amdgcn_mfma_f32_16x16x32_bf16(qh[ks], kh1, s1, 0, 0, 0);
        s1 = __builtin_amdgcn_mfma_f32_16x16x32_bf16(qh[ks], kl1, s1, 0, 0, 0);
        s1 = __builtin_amdgcn_mfma_f32_16x16x32_bf16(ql[ks], kh1, s1, 0, 0, 0);
      }

      float mloc[4];
#pragma unroll
      for (int rr = 0; rr < 4; ++rr) {
        const int qg = q0 + w * 16 + g * 4 + rr;
        float a0 = (k0 + r16 <= qg) ? s0[rr] * sscale : -INFINITY;
        float a1 = (k0 + 16 + r16 <= qg) ? s1[rr] * sscale : -INFINITY;
        s0[rr] = a0; s1[rr] = a1;
        mloc[rr] = fmaxf(a0, a1);
      }
#pragma unroll
      for (int off = 1; off < 16; off <<= 1)
#pragma unroll
        for (int rr = 0; rr < 4; ++rr) mloc[rr] = fmaxf(mloc[rr], __shfl_xor(mloc[rr], off));
      float alpha[4], lsum[4];
#pragma unroll
      for (int rr = 0; rr < 4; ++rr) {
        const float mnew = fmaxf(m[rr], mloc[rr]);
        alpha[rr] = __expf(m[rr] - mnew);
        m[rr] = mnew;
        const float p0 = __expf(s0[rr] - mnew);
        const float p1 = __expf(s1[rr] - mnew);
        s0[rr] = p0; s1[rr] = p1;
        lsum[rr] = p0 + p1;
      }
#pragma unroll
      for (int off = 1; off < 16; off <<= 1)
#pragma unroll
        for (int rr = 0; rr < 4; ++rr) lsum[rr] += __shfl_xor(lsum[rr], off);
#pragma unroll
      for (int rr = 0; rr < 4; ++rr) l[rr] = l[rr] * alpha[rr] + lsum[rr];
#pragma unroll
      for (int dt = 0; dt < 8; ++dt)
#pragma unroll
        for (int rr = 0; rr < 4; ++rr) o[dt][rr] *= alpha[rr];

#pragma unroll
      for (int rr = 0; rr < 4; ++rr) {
        const int q = g * 4 + rr;
        unsigned short hh, ll;
        cvt_split(s0[rr], hh, ll);
        Pws[w][0][q * 40 + r16] = hh; Pws[w][1][q * 40 + r16] = ll;
        cvt_split(s1[rr], hh, ll);
        Pws[w][0][q * 40 + 16 + r16] = hh; Pws[w][1][q * 40 + 16 + r16] = ll;
      }
      // wave-private P region: same-wave LDS write->read is ordered

      bf16x8 pah = *(const bf16x8*)&Pws[w][0][r16 * 40 + g * 8];
      bf16x8 pal = *(const bf16x8*)&Pws[w][1][r16 * 40 + g * 8];
#pragma unroll
      for (int dt = 0; dt < 8; ++dt) {
        const int d = dt * 16 + r16;
        bf16x8 vh = *(const bf16x8*)&Vsh[0][d][g * 8];
        bf16x8 vl = *(const bf16x8*)&Vsh[1][d][g * 8];
        o[dt] = __builtin_amdgcn_mfma_f32_16x16x32_bf16(pah, vh, o[dt], 0, 0, 0);
        o[dt] = __builtin_amdgcn_mfma_f32_16x16x32_bf16(pah, vl, o[dt], 0, 0, 0);
        o[dt] = __builtin_amdgcn_mfma_f32_16x16x32_bf16(pal, vh, o[dt], 0, 0, 0);
      }
    }

    // ---- epilogue: write O pre-split (hi/lo) ----
    float inv[4];
#pragma unroll
    for (int rr = 0; rr < 4; ++rr) inv[rr] = 1.f / l[rr];
#pragma unroll
    for (int dt = 0; dt < 8; ++dt)
#pragma unroll
      for (int rr = 0; rr < 4; ++rr) {
        const size_t oidx =
            (size_t)(b * Tn + q0 + w * 16 + g * 4 + rr) * (NH * HD) + h * HD + dt * 16 + r16;
        unsigned short hi, lo;
        cvt_split(o[dt][rr] * inv[rr], hi, lo);
        Oh[oidx] = hi;
        Ol[oidx] = lo;
      }
  }
}

extern "C" void kernel_launch(void* const* d_in, const int* in_sizes, int n_in,
                              void* d_out, int out_size, void* d_ws, size_t ws_size,
                              hipStream_t stream) {
  const float* x = (const float*)d_in[0];
  const float* Wq = (const float*)d_in[1];
  const float* Wk = (const float*)d_in[2];
  const float* Wv = (const float*)d_in[3];
  const float* Wo = (const float*)d_in[4];
  const float* q_scale = (const float*)d_in[5];
  const float* k_scale = (const float*)d_in[6];
  float* out = (float*)d_out;

  const int R = Bn * Tn;
  // ---- workspace layout (~126 MB) ----
  unsigned short* p = (unsigned short*)d_ws;
  unsigned short* Wqh = p; p += (size_t)2048 * 2048;
  unsigned short* Wql = p; p += (size_t)2048 * 2048;
  unsigned short* Wkh = p; p += (size_t)512 * 2048;
  unsigned short* Wkl = p; p += (size_t)512 * 2048;
  unsigned short* Wvh = p; p += (size_t)512 * 2048;
  unsigned short* Wvl = p; p += (size_t)512 * 2048;
  unsigned short* Woh = p; p += (size_t)2048 * 2048;
  unsigned short* Wol = p; p += (size_t)2048 * 2048;
  unsigned short* Oh = p; p += (size_t)R * 2048;
  unsigned short* Ol = p; p += (size_t)R * 2048;
  unsigned short* Vt = p; p += (size_t)Bn * NKV * 64 * 8192;
  float* Q = (float*)p;                       // [R][2048] fp32 -> hi|lo ush
  float* K = Q + (size_t)R * (NH * HD);       // [R][512]

  dim3 blk(256);
  // Pre-split weights (memory-bound preps)
  split_kernel<<<dim3(2048), blk, 0, stream>>>(Wq, Wqh, Wql, 2048 * 2048 / 4);
  split_kernel<<<dim3(1024), blk, 0, stream>>>(Wk, Wkh, Wkl, 512 * 2048 / 4);
  split_kernel<<<dim3(1024), blk, 0, stream>>>(Wv, Wvh, Wvl, 512 * 2048 / 4);
  split_kernel<<<dim3(2048), blk, 0, stream>>>(Wo, Woh, Wol, 2048 * 2048 / 4);
  // Q/K/V projections (B via DMA, A=x cvt in-loop)
  qkv_kernel<<<dim3(24, R / 128), blk, 0, stream>>>(x, Wqh, Wql, Wkh, Wkl, Wvh, Wvl, Q, K, Vt);
  // RMS-norm + in-place split-cvt
  rmsnorm_cvt_kernel<<<dim3(R * NH / 4), blk, 0, stream>>>(Q, q_scale);
  rmsnorm_cvt_kernel<<<dim3(R * NKV / 4), blk, 0, stream>>>(K, k_scale);
  // MFMA flash attention (writes O pre-split)
  attn_kernel<<<dim3(16, NH, Bn), blk, 0, stream>>>(
      (const unsigned short*)Q, (const unsigned short*)K, Vt, Oh, Ol);
  // Output projection (both operands via DMA)
  oproj_kernel<<<dim3(DM / 128, R / 128), blk, 0, stream>>>(Oh, Ol, Woh, Wol, out);
}